// Round 1
// baseline (668.237 us; speedup 1.0000x reference)
//
#include <hip/hip_runtime.h>

#define N_NODES 10000
#define N_RELS  50
#define R_AUG   101
#define D       128
#define N_EDGES 320000
#define E_AUG   650000   /* 2*N_EDGES + N_NODES */
#define N_BATCH 65536

#define NP      (R_AUG * N_NODES)            /* 1,010,000 (rel,dst) bins */
#define NPB4    ((NP + 1023) / 1024)         /* 987 scan blocks (4 elem/thread) */
#define SCAT_BLOCKS ((E_AUG + 255) / 256)    /* 2540 */

/* fused prep kernel block ranges: hist FIRST (latency-bound atomics start at t=0) */
#define HIST_BLOCKS  2540                    /* ceil(E_AUG/256) */
#define TW_BLOCKS    808                     /* 2*2*(2*R_AUG) */
#define PREPX_BLOCKS 1250                    /* N_NODES*D/(256*4) */

/* fused layer geometry */
#define DSPAN   32
#define NDBLK   ((N_NODES + DSPAN - 1) / DSPAN)   /* 313 */
#define RSPLIT  2
#define FUSE_BLOCKS (NDBLK * RSPLIT)              /* 626 */
#define R_HALF  51                                /* rels [0,51) and [51,101) */

typedef short bf16x8 __attribute__((ext_vector_type(8)));
typedef float f32x4  __attribute__((ext_vector_type(4)));

__device__ __forceinline__ unsigned short f2bf(float f) {
    union { float f; unsigned int u; } v; v.f = f;
    unsigned int r = (v.u + 0x7FFFu + ((v.u >> 16) & 1u)) >> 16;
    return (unsigned short)r;
}
__device__ __forceinline__ float bf2f(unsigned short h) {
    union { unsigned int u; float f; } v; v.u = ((unsigned int)h) << 16;
    return v.f;
}

__device__ __forceinline__ void decode_edge(const int* __restrict__ g, int e,
                                            int& src, int& rel, int& dst) {
    if (e < N_EDGES)            { src = g[3*e];     rel = g[3*e+1];          dst = g[3*e+2]; }
    else if (e < 2*N_EDGES)     { int b = e - N_EDGES;
                                  src = g[3*b+2];   rel = g[3*b+1] + N_RELS; dst = g[3*b];   }
    else                        { int n = e - 2*N_EDGES; src = n; dst = n; rel = 2*N_RELS;   }
}

// ---------------- fused prep: deg_hist | transpose_w | x->bf16 ----------------

__global__ __launch_bounds__(256) void prep_all(const float* __restrict__ x,
                                                unsigned short* __restrict__ xb,
                                                const float* __restrict__ W1,
                                                const float* __restrict__ W2,
                                                unsigned short* __restrict__ W1t,
                                                unsigned short* __restrict__ W2t,
                                                const int* __restrict__ g,
                                                int* __restrict__ deg) {
    __shared__ float tile[64][65];
    int b = blockIdx.x, t = threadIdx.x;
    if (b < HIST_BLOCKS) {
        int e = b * 256 + t;
        if (e < E_AUG) {
            int src, rel, dst;
            decode_edge(g, e, src, rel, dst);
            (void)src;
            atomicAdd(&deg[rel * N_NODES + dst], 1);
        }
    } else if (b < HIST_BLOCKS + TW_BLOCKS) {
        int q = b - HIST_BLOCKS;
        int d0 = (q & 1) * 64, o0 = ((q >> 1) & 1) * 64;
        int z = q >> 2;                                  /* 0..201 */
        const float* W = (z < R_AUG) ? W1 : W2;
        unsigned short* Wt = (z < R_AUG) ? W1t : W2t;
        int r = (z < R_AUG) ? z : (z - R_AUG);
        int tx = t & 63, ty = t >> 6;
        #pragma unroll
        for (int i = ty; i < 64; i += 4)
            tile[i][tx] = W[((size_t)r * D + (d0 + i)) * D + (o0 + tx)];
        __syncthreads();
        #pragma unroll
        for (int i = ty; i < 64; i += 4)
            Wt[((size_t)r * D + (o0 + i)) * D + (d0 + tx)] = f2bf(tile[tx][i]);
    } else {
        int i = (b - HIST_BLOCKS - TW_BLOCKS) * 1024 + t * 4;  // covers N_NODES*D exactly
        float4 xv = *(const float4*)(x + i);
        ushort4 o;
        o.x = f2bf(xv.x); o.y = f2bf(xv.y); o.z = f2bf(xv.z); o.w = f2bf(xv.w);
        *(ushort4*)(xb + i) = o;
    }
}

// ---- scan A: per-block exclusive scan of deg[NP] (4 elem/thread) ----

__global__ __launch_bounds__(256) void scan_a(const int* __restrict__ deg,
                                              int* __restrict__ binoff,
                                              int* __restrict__ ppart) {
    __shared__ int wsum[4];
    int t = threadIdx.x, lane = t & 63, w = t >> 6;
    int i0 = blockIdx.x * 1024 + t * 4;
    int4 d = {0, 0, 0, 0};
    if (i0 < NP) d = *(const int4*)(deg + i0);          // NP % 4 == 0, safe
    int e1 = d.x, e2 = e1 + d.y, e3 = e2 + d.z, v = e3 + d.w;
    int incl = v;
    #pragma unroll
    for (int off = 1; off < 64; off <<= 1) {
        int u = __shfl_up(incl, off, 64);
        if (lane >= off) incl += u;
    }
    if (lane == 63) wsum[w] = incl;
    __syncthreads();
    int woff = 0;
    for (int k = 0; k < w; k++) woff += wsum[k];
    int texcl = woff + incl - v;
    if (i0 < NP) {
        int4 o = {texcl, texcl + e1, texcl + e2, texcl + e3};
        *(int4*)(binoff + i0) = o;
    }
    if (t == 255) ppart[blockIdx.x] = woff + incl;
}

// ---- scan B: single block serial-carry over ppart[NPB4]; binoff[NP] = total ----

__global__ __launch_bounds__(256) void scan_b(int* __restrict__ ppart,
                                              int* __restrict__ binoff) {
    __shared__ int wsum[4];
    int t = threadIdx.x, lane = t & 63, w = t >> 6;
    int carry = 0;
    for (int base = 0; base < NPB4; base += 256) {
        int i = base + t;
        int v = (i < NPB4) ? ppart[i] : 0;
        int incl = v;
        #pragma unroll
        for (int off = 1; off < 64; off <<= 1) {
            int u = __shfl_up(incl, off, 64);
            if (lane >= off) incl += u;
        }
        if (lane == 63) wsum[w] = incl;
        __syncthreads();
        int woff = 0;
        for (int k = 0; k < w; k++) woff += wsum[k];
        if (i < NPB4) ppart[i] = carry + woff + incl - v;
        carry += wsum[0] + wsum[1] + wsum[2] + wsum[3];
        __syncthreads();
    }
    if (t == 0) binoff[NP] = carry;
}

// ---- scan C: add block offsets; init cursor = binoff ----

__global__ __launch_bounds__(256) void scan_c(int* __restrict__ binoff,
                                              const int* __restrict__ ppart,
                                              int* __restrict__ cursor) {
    int i0 = blockIdx.x * 1024 + threadIdx.x * 4;
    if (i0 >= NP) return;
    int pp = ppart[blockIdx.x];
    int4 sv = *(int4*)(binoff + i0);
    sv.x += pp; sv.y += pp; sv.z += pp; sv.w += pp;
    *(int4*)(binoff + i0) = sv;
    *(int4*)(cursor + i0) = sv;
}

// ---- edge scatter: sorted by (rel, dst) bin; record = src (ushort) ----

__global__ __launch_bounds__(256) void scatter_edges(const int* __restrict__ g,
                                                     int* __restrict__ cursor,
                                                     unsigned short* __restrict__ esrc) {
    int e = blockIdx.x * 256 + threadIdx.x;
    if (e >= E_AUG) return;
    int src, rel, dst;
    decode_edge(g, e, src, rel, dst);
    int pos = atomicAdd(&cursor[rel * N_NODES + dst], 1);
    esrc[pos] = (unsigned short)src;
}

// ---------------- fused layer: per block (32 dsts x rel-half) ----------------
// Per rel: aggregate present bins into LDS bf16 tile (double buffered), then
// MFMA against W[r] streamed from L2, accumulate into hblk[32][128] f32 LDS.
// Wave w owns output cols [w*32, w*32+32). aggbuf XOR-swizzled ((row&7)<<4 on
// bytes, 16B granule); hblk XOR-swizzled ((row&7)<<5, 32B granule) -- G4: raw
// row strides 256B/512B are 16-way bank conflicts on ds_read_b128.

__global__ __launch_bounds__(256, 2) void fused_layer(const unsigned short* __restrict__ xb,
                                                      const unsigned short* __restrict__ Wt,
                                                      const int* __restrict__ binoff,
                                                      const unsigned short* __restrict__ esrc,
                                                      float* __restrict__ hpart) {
    __shared__ __align__(16) char aggbuf[2][DSPAN * D * 2];   // bf16 tiles, 16 KB
    __shared__ __align__(16) char hblk[DSPAN * D * 4];        // f32 accum, 16 KB
    __shared__ int bbase[2][DSPAN];
    __shared__ int bpack[2][DSPAN];                           // (deg<<8)|dloc

    int b = blockIdx.x;
    int half = b & 1, dblk = b >> 1;
    int dst0 = dblk * DSPAN;
    int r0 = half ? R_HALF : 0;
    int r1 = half ? R_AUG : R_HALF;

    int t = threadIdx.x, w = t >> 6, lane = t & 63;
    int lr = lane & 15, lq = lane >> 4;

    // zero hblk (visible to all waves after prologue barrier)
    #pragma unroll
    for (int i = t * 4; i < DSPAN * D; i += 1024) {
        float4 z = {0.f, 0.f, 0.f, 0.f};
        *(float4*)(hblk + (size_t)i * 4) = z;
    }

    // ---------- aggregation of one rel into buffer B; returns nbins ----------
    auto agg_rel = [&](int r, int B) -> int {
        // metadata: lanes 0..32 load binoff; deg via shfl_down diff
        int j = lane;
        int bj = 0;
        if (j <= DSPAN) {
            int jj = dst0 + j;
            if (jj > N_NODES) jj = N_NODES;          // tail-block clamp -> deg 0
            bj = binoff[r * N_NODES + jj];
        }
        int bnext = __shfl_down(bj, 1, 64);
        int dg = (j < DSPAN) ? (bnext - bj) : 0;
        unsigned long long m = __ballot(dg > 0);
        unsigned int mask = (unsigned int)m;          // bits 0..31 only
        int nb = __popc(mask);
        int cb = __popc(mask & ((j < 32) ? ((1u << j) - 1u) : 0xFFFFFFFFu));
        if (j < DSPAN && dg > 0 && (cb & 3) == w) {   // each rec written by its owner wave
            bbase[B][cb] = bj;
            bpack[B][cb] = (dg << 8) | j;
        }
        // wave w processes bins cb = w, w+4, ... (records written by own wave)
        int mbase[8], mdeg[8];
        #pragma unroll
        for (int i = 0; i < 8; i++) {
            int c = w + 4 * i;
            if (c < nb) { mbase[i] = bbase[B][c]; mdeg[i] = bpack[B][c] >> 8; }
            else        { mbase[i] = 0;           mdeg[i] = 0; }
        }
        float a0[8], a1[8];
        #pragma unroll
        for (int i = 0; i < 8; i++) { a0[i] = 0.f; a1[i] = 0.f; }
        int k = 0;
        bool any = (w < nb);
        while (any) {
            any = false;
            int sv[8];
            unsigned int xv[8];
            #pragma unroll
            for (int i = 0; i < 8; i++)
                if (k < mdeg[i]) sv[i] = esrc[mbase[i] + k];
            #pragma unroll
            for (int i = 0; i < 8; i++)
                if (k < mdeg[i]) xv[i] = *(const unsigned int*)(xb + (size_t)sv[i] * D + lane * 2);
            #pragma unroll
            for (int i = 0; i < 8; i++)
                if (k < mdeg[i]) {
                    a0[i] += bf2f((unsigned short)(xv[i] & 0xFFFFu));
                    a1[i] += bf2f((unsigned short)(xv[i] >> 16));
                    if (k + 1 < mdeg[i]) any = true;
                }
            k++;
        }
        #pragma unroll
        for (int i = 0; i < 8; i++)
            if (mdeg[i] > 0) {
                float s = 1.0f / (float)mdeg[i];
                unsigned int pk = (unsigned)f2bf(a0[i] * s) | ((unsigned)f2bf(a1[i] * s) << 16);
                int c = w + 4 * i;
                int byteoff = (c * 256 + lane * 4) ^ ((c & 7) << 4);
                *(unsigned int*)(aggbuf[B] + byteoff) = pk;
            }
        return nb;
    };

    // ---------- MFMA of one rel from buffer B ----------
    int no = w * 32;
    int prow = ((lr >> 2) << 3) + (lr & 3);
    auto mfma_rel = [&](int r, int B, int nb) {
        if (nb <= 0) return;
        const unsigned short* Wr = Wt + (size_t)r * D * D;
        bf16x8 w0[4], w1[4];
        #pragma unroll
        for (int ks = 0; ks < 4; ks++) {
            size_t kb = (size_t)ks * 32 + lq * 8;
            w0[ks] = *(const bf16x8*)(Wr + (size_t)(no + prow) * D + kb);
            w1[ks] = *(const bf16x8*)(Wr + (size_t)(no + prow + 4) * D + kb);
        }
        // tile 0: bins 0..15
        {
            f32x4 c0 = {}, c1 = {};
            #pragma unroll
            for (int ks = 0; ks < 4; ks++) {
                int byteoff = (lr * 256 + ks * 64 + lq * 16) ^ ((lr & 7) << 4);
                bf16x8 a = *(const bf16x8*)(aggbuf[B] + byteoff);
                c0 = __builtin_amdgcn_mfma_f32_16x16x32_bf16(w0[ks], a, c0, 0, 0, 0);
                c1 = __builtin_amdgcn_mfma_f32_16x16x32_bf16(w1[ks], a, c1, 0, 0, 0);
            }
            if (lr < nb) {
                int dloc = bpack[B][lr] & 63;
                int cbyte = (no + lq * 8) * 4;
                char* hp0 = hblk + (((dloc * 512) + cbyte) ^ ((dloc & 7) << 5));
                char* hp1 = hblk + (((dloc * 512) + cbyte + 16) ^ ((dloc & 7) << 5));
                float4 h0 = *(float4*)hp0;
                h0.x += c0[0]; h0.y += c0[1]; h0.z += c0[2]; h0.w += c0[3];
                *(float4*)hp0 = h0;
                float4 h1 = *(float4*)hp1;
                h1.x += c1[0]; h1.y += c1[1]; h1.z += c1[2]; h1.w += c1[3];
                *(float4*)hp1 = h1;
            }
        }
        // tile 1: bins 16..31
        if (nb > 16) {
            f32x4 c2 = {}, c3 = {};
            int rrow = 16 + lr;
            #pragma unroll
            for (int ks = 0; ks < 4; ks++) {
                int byteoff = (rrow * 256 + ks * 64 + lq * 16) ^ ((rrow & 7) << 4);
                bf16x8 a = *(const bf16x8*)(aggbuf[B] + byteoff);
                c2 = __builtin_amdgcn_mfma_f32_16x16x32_bf16(w0[ks], a, c2, 0, 0, 0);
                c3 = __builtin_amdgcn_mfma_f32_16x16x32_bf16(w1[ks], a, c3, 0, 0, 0);
            }
            if (rrow < nb) {
                int dloc = bpack[B][rrow] & 63;
                int cbyte = (no + lq * 8) * 4;
                char* hp0 = hblk + (((dloc * 512) + cbyte) ^ ((dloc & 7) << 5));
                char* hp1 = hblk + (((dloc * 512) + cbyte + 16) ^ ((dloc & 7) << 5));
                float4 h0 = *(float4*)hp0;
                h0.x += c2[0]; h0.y += c2[1]; h0.z += c2[2]; h0.w += c2[3];
                *(float4*)hp0 = h0;
                float4 h1 = *(float4*)hp1;
                h1.x += c3[0]; h1.y += c3[1]; h1.z += c3[2]; h1.w += c3[3];
                *(float4*)hp1 = h1;
            }
        }
    };

    // ---------- pipelined rel loop: agg(r+1) issues loads before mfma(r) ----------
    int nbC = agg_rel(r0, 0);
    __syncthreads();
    int cur = 0;
    for (int r = r0; r < r1; r++) {
        int nbN = 0;
        if (r + 1 < r1) nbN = agg_rel(r + 1, cur ^ 1);
        mfma_rel(r, cur, nbC);
        __syncthreads();
        nbC = nbN;
        cur ^= 1;
    }

    // ---------- writeback: hblk -> hpart[half] (raw sums, bias/relu in finish) ----------
    int row = t >> 3, c0b = (t & 7) * 16;
    int dst = dst0 + row;
    if (dst < N_NODES) {
        float* outp = hpart + (size_t)half * N_NODES * D + (size_t)dst * D;
        #pragma unroll
        for (int q = 0; q < 4; q++) {
            int cb = c0b + q * 4;
            float4 v = *(float4*)(hblk + (((row * 512) + cb * 4) ^ ((row & 7) << 5)));
            *(float4*)(outp + cb) = v;
        }
    }
}

// ---------------- finish: h = act(hp0 + hp1 + bias) ----------------

__global__ __launch_bounds__(256) void finish(const float* __restrict__ hpart,
                                              const float* __restrict__ bias,
                                              float* __restrict__ hf,
                                              unsigned short* __restrict__ hb,
                                              int dorelu) {
    int i0 = (blockIdx.x * 256 + threadIdx.x) * 8;      // grid 625 covers N_NODES*D exactly
    int c0 = i0 & 127;
    const float* p0 = hpart + i0;
    const float* p1 = hpart + (size_t)N_NODES * D + i0;
    float4 x0 = *(const float4*)p0,        x1 = *(const float4*)(p0 + 4);
    float4 y0 = *(const float4*)p1,        y1 = *(const float4*)(p1 + 4);
    float4 b0 = *(const float4*)(bias + c0), b1 = *(const float4*)(bias + c0 + 4);
    float v[8];
    v[0] = x0.x + y0.x + b0.x; v[1] = x0.y + y0.y + b0.y;
    v[2] = x0.z + y0.z + b0.z; v[3] = x0.w + y0.w + b0.w;
    v[4] = x1.x + y1.x + b1.x; v[5] = x1.y + y1.y + b1.y;
    v[6] = x1.z + y1.z + b1.z; v[7] = x1.w + y1.w + b1.w;
    if (dorelu) {
        uint4 p;
        p.x = (unsigned)f2bf(fmaxf(v[0], 0.f)) | ((unsigned)f2bf(fmaxf(v[1], 0.f)) << 16);
        p.y = (unsigned)f2bf(fmaxf(v[2], 0.f)) | ((unsigned)f2bf(fmaxf(v[3], 0.f)) << 16);
        p.z = (unsigned)f2bf(fmaxf(v[4], 0.f)) | ((unsigned)f2bf(fmaxf(v[5], 0.f)) << 16);
        p.w = (unsigned)f2bf(fmaxf(v[6], 0.f)) | ((unsigned)f2bf(fmaxf(v[7], 0.f)) << 16);
        *(uint4*)(hb + i0) = p;
    } else {
        float4 o0 = {v[0], v[1], v[2], v[3]};
        float4 o1 = {v[4], v[5], v[6], v[7]};
        *(float4*)(hf + i0) = o0;
        *(float4*)(hf + i0 + 4) = o1;
    }
}

// ---------------- scoring: 4 items/wave (16 lanes x 2 float4 each) ----------------

__global__ __launch_bounds__(256) void score_kernel(const int* __restrict__ batch,
                                                    const float* __restrict__ h2,
                                                    const float* __restrict__ rels,
                                                    float* __restrict__ out) {
    int t = threadIdx.x;
    int wv = t >> 6, q = (t & 63) >> 4, sl = t & 15;
    int i = blockIdx.x * 16 + wv * 4 + q;     // grid 4096 covers 65536 exactly
    int bs = batch[3*i], bp = batch[3*i+1], bo = batch[3*i+2];
    const float* sp = h2   + (size_t)bs * D + sl * 8;
    const float* pp = rels + (size_t)bp * D + sl * 8;
    const float* op = h2   + (size_t)bo * D + sl * 8;
    float4 s0 = *(const float4*)sp,      s1 = *(const float4*)(sp + 4);
    float4 p0 = *(const float4*)pp,      p1 = *(const float4*)(pp + 4);
    float4 o0 = *(const float4*)op,      o1 = *(const float4*)(op + 4);
    float v = s0.x * p0.x * o0.x + s0.y * p0.y * o0.y + s0.z * p0.z * o0.z + s0.w * p0.w * o0.w
            + s1.x * p1.x * o1.x + s1.y * p1.y * o1.y + s1.z * p1.z * o1.z + s1.w * p1.w * o1.w;
    #pragma unroll
    for (int off = 8; off > 0; off >>= 1) v += __shfl_down(v, off, 16);
    if (sl == 0) out[i] = v;
}

// ---------------- host ----------------

extern "C" void kernel_launch(void* const* d_in, const int* in_sizes, int n_in,
                              void* d_out, int out_size, void* d_ws, size_t ws_size,
                              hipStream_t stream) {
    const int*   graph = (const int*)  d_in[0];
    const int*   batch = (const int*)  d_in[1];
    const float* emb   = (const float*)d_in[2];
    const float* W1    = (const float*)d_in[3];
    const float* b1    = (const float*)d_in[4];
    const float* W2    = (const float*)d_in[5];
    const float* b2    = (const float*)d_in[6];
    const float* rels  = (const float*)d_in[7];
    float* out = (float*)d_out;

    char* base = (char*)d_ws;
    size_t off = 0;
    auto take = [&](size_t bytes) -> char* {
        char* q = base + off;
        off += (bytes + 255) & ~(size_t)255;
        return q;
    };
    int*            deg     = (int*)           take((size_t)NP * 4);
    int*            binoff  = (int*)           take((size_t)(NP + 1) * 4);
    int*            cursor  = (int*)           take((size_t)NP * 4);
    int*            ppart   = (int*)           take((size_t)NPB4 * 4);
    unsigned short* esrc    = (unsigned short*)take((size_t)E_AUG * 2);
    unsigned short* xb      = (unsigned short*)take((size_t)N_NODES * D * 2);
    unsigned short* h1b     = (unsigned short*)take((size_t)N_NODES * D * 2);
    float*          h2      = (float*)         take((size_t)N_NODES * D * 4);
    unsigned short* W1t     = (unsigned short*)take((size_t)R_AUG * D * D * 2);
    unsigned short* W2t     = (unsigned short*)take((size_t)R_AUG * D * D * 2);
    float*          hpart   = (float*)         take((size_t)RSPLIT * N_NODES * D * 4);

    hipMemsetAsync(deg, 0, (size_t)NP * 4, stream);
    prep_all<<<dim3(HIST_BLOCKS + TW_BLOCKS + PREPX_BLOCKS), 256, 0, stream>>>(
        emb, xb, W1, W2, W1t, W2t, graph, deg);
    scan_a<<<dim3(NPB4), 256, 0, stream>>>(deg, binoff, ppart);
    scan_b<<<dim3(1), 256, 0, stream>>>(ppart, binoff);
    scan_c<<<dim3(NPB4), 256, 0, stream>>>(binoff, ppart, cursor);
    scatter_edges<<<dim3(SCAT_BLOCKS), 256, 0, stream>>>(graph, cursor, esrc);

    fused_layer<<<dim3(FUSE_BLOCKS), 256, 0, stream>>>(xb, W1t, binoff, esrc, hpart);
    finish<<<dim3(625), 256, 0, stream>>>(hpart, b1, (float*)0, h1b, 1);
    fused_layer<<<dim3(FUSE_BLOCKS), 256, 0, stream>>>(h1b, W2t, binoff, esrc, hpart);
    finish<<<dim3(625), 256, 0, stream>>>(hpart, b2, h2, (unsigned short*)0, 0);
    score_kernel<<<dim3(N_BATCH / 16), 256, 0, stream>>>(batch, h2, rels, out);
}

// Round 2
// 541.680 us; speedup vs baseline: 1.2336x; 1.2336x over previous
//
#include <hip/hip_runtime.h>

#define N_NODES 10000
#define N_RELS  50
#define R_AUG   101
#define D       128
#define N_EDGES 320000
#define E_AUG   650000   /* 2*N_EDGES + N_NODES */
#define N_BATCH 65536

#define NP      (R_AUG * N_NODES)            /* 1,010,000 (rel,dst) bins */
#define NPB4    ((NP + 1023) / 1024)         /* 987 scan blocks (4 elem/thread) */
#define SCAT_BLOCKS ((E_AUG + 255) / 256)    /* 2540 */

/* fused prep kernel block ranges: hist FIRST (latency-bound atomics start at t=0) */
#define HIST_BLOCKS  2540                    /* ceil(E_AUG/256) */
#define TW_BLOCKS    808                     /* 2*2*(2*R_AUG) */
#define PREPX_BLOCKS 1250                    /* N_NODES*D/(256*4) */

/* fused layer geometry: 64 dsts x 1/8 of rels per block */
#define DSPAN   64
#define NDBLK   ((N_NODES + DSPAN - 1) / DSPAN)   /* 157 */
#define RSPLIT  8
#define FUSE_BLOCKS (NDBLK * RSPLIT)              /* 1256 */
#define NRMAX   13

typedef short bf16x8 __attribute__((ext_vector_type(8)));
typedef float f32x4  __attribute__((ext_vector_type(4)));

__device__ __forceinline__ unsigned short f2bf(float f) {
    union { float f; unsigned int u; } v; v.f = f;
    unsigned int r = (v.u + 0x7FFFu + ((v.u >> 16) & 1u)) >> 16;
    return (unsigned short)r;
}
__device__ __forceinline__ float bf2f(unsigned short h) {
    union { unsigned int u; float f; } v; v.u = ((unsigned int)h) << 16;
    return v.f;
}

__device__ __forceinline__ void decode_edge(const int* __restrict__ g, int e,
                                            int& src, int& rel, int& dst) {
    if (e < N_EDGES)            { src = g[3*e];     rel = g[3*e+1];          dst = g[3*e+2]; }
    else if (e < 2*N_EDGES)     { int b = e - N_EDGES;
                                  src = g[3*b+2];   rel = g[3*b+1] + N_RELS; dst = g[3*b];   }
    else                        { int n = e - 2*N_EDGES; src = n; dst = n; rel = 2*N_RELS;   }
}

// ---------------- fused prep: deg_hist | transpose_w | x->bf16 ----------------

__global__ __launch_bounds__(256) void prep_all(const float* __restrict__ x,
                                                unsigned short* __restrict__ xb,
                                                const float* __restrict__ W1,
                                                const float* __restrict__ W2,
                                                unsigned short* __restrict__ W1t,
                                                unsigned short* __restrict__ W2t,
                                                const int* __restrict__ g,
                                                int* __restrict__ deg) {
    __shared__ float tile[64][65];
    int b = blockIdx.x, t = threadIdx.x;
    if (b < HIST_BLOCKS) {
        int e = b * 256 + t;
        if (e < E_AUG) {
            int src, rel, dst;
            decode_edge(g, e, src, rel, dst);
            (void)src;
            atomicAdd(&deg[rel * N_NODES + dst], 1);
        }
    } else if (b < HIST_BLOCKS + TW_BLOCKS) {
        int q = b - HIST_BLOCKS;
        int d0 = (q & 1) * 64, o0 = ((q >> 1) & 1) * 64;
        int z = q >> 2;                                  /* 0..201 */
        const float* W = (z < R_AUG) ? W1 : W2;
        unsigned short* Wt = (z < R_AUG) ? W1t : W2t;
        int r = (z < R_AUG) ? z : (z - R_AUG);
        int tx = t & 63, ty = t >> 6;
        #pragma unroll
        for (int i = ty; i < 64; i += 4)
            tile[i][tx] = W[((size_t)r * D + (d0 + i)) * D + (o0 + tx)];
        __syncthreads();
        #pragma unroll
        for (int i = ty; i < 64; i += 4)
            Wt[((size_t)r * D + (o0 + i)) * D + (d0 + tx)] = f2bf(tile[tx][i]);
    } else {
        int i = (b - HIST_BLOCKS - TW_BLOCKS) * 1024 + t * 4;  // covers N_NODES*D exactly
        float4 xv = *(const float4*)(x + i);
        ushort4 o;
        o.x = f2bf(xv.x); o.y = f2bf(xv.y); o.z = f2bf(xv.z); o.w = f2bf(xv.w);
        *(ushort4*)(xb + i) = o;
    }
}

// ---- scan A: per-block exclusive scan of deg[NP] (4 elem/thread) ----

__global__ __launch_bounds__(256) void scan_a(const int* __restrict__ deg,
                                              int* __restrict__ binoff,
                                              int* __restrict__ ppart) {
    __shared__ int wsum[4];
    int t = threadIdx.x, lane = t & 63, w = t >> 6;
    int i0 = blockIdx.x * 1024 + t * 4;
    int4 d = {0, 0, 0, 0};
    if (i0 < NP) d = *(const int4*)(deg + i0);          // NP % 4 == 0, safe
    int e1 = d.x, e2 = e1 + d.y, e3 = e2 + d.z, v = e3 + d.w;
    int incl = v;
    #pragma unroll
    for (int off = 1; off < 64; off <<= 1) {
        int u = __shfl_up(incl, off, 64);
        if (lane >= off) incl += u;
    }
    if (lane == 63) wsum[w] = incl;
    __syncthreads();
    int woff = 0;
    for (int k = 0; k < w; k++) woff += wsum[k];
    int texcl = woff + incl - v;
    if (i0 < NP) {
        int4 o = {texcl, texcl + e1, texcl + e2, texcl + e3};
        *(int4*)(binoff + i0) = o;
    }
    if (t == 255) ppart[blockIdx.x] = woff + incl;
}

// ---- scan B: single block serial-carry over ppart[NPB4]; binoff[NP] = total ----

__global__ __launch_bounds__(256) void scan_b(int* __restrict__ ppart,
                                              int* __restrict__ binoff) {
    __shared__ int wsum[4];
    int t = threadIdx.x, lane = t & 63, w = t >> 6;
    int carry = 0;
    for (int base = 0; base < NPB4; base += 256) {
        int i = base + t;
        int v = (i < NPB4) ? ppart[i] : 0;
        int incl = v;
        #pragma unroll
        for (int off = 1; off < 64; off <<= 1) {
            int u = __shfl_up(incl, off, 64);
            if (lane >= off) incl += u;
        }
        if (lane == 63) wsum[w] = incl;
        __syncthreads();
        int woff = 0;
        for (int k = 0; k < w; k++) woff += wsum[k];
        if (i < NPB4) ppart[i] = carry + woff + incl - v;
        carry += wsum[0] + wsum[1] + wsum[2] + wsum[3];
        __syncthreads();
    }
    if (t == 0) binoff[NP] = carry;
}

// ---- scan C: add block offsets; init cursor = binoff ----

__global__ __launch_bounds__(256) void scan_c(int* __restrict__ binoff,
                                              const int* __restrict__ ppart,
                                              int* __restrict__ cursor) {
    int i0 = blockIdx.x * 1024 + threadIdx.x * 4;
    if (i0 >= NP) return;
    int pp = ppart[blockIdx.x];
    int4 sv = *(int4*)(binoff + i0);
    sv.x += pp; sv.y += pp; sv.z += pp; sv.w += pp;
    *(int4*)(binoff + i0) = sv;
    *(int4*)(cursor + i0) = sv;
}

// ---- edge scatter: sorted by (rel, dst) bin; record = src (ushort) ----

__global__ __launch_bounds__(256) void scatter_edges(const int* __restrict__ g,
                                                     int* __restrict__ cursor,
                                                     unsigned short* __restrict__ esrc) {
    int e = blockIdx.x * 256 + threadIdx.x;
    if (e >= E_AUG) return;
    int src, rel, dst;
    decode_edge(g, e, src, rel, dst);
    int pos = atomicAdd(&cursor[rel * N_NODES + dst], 1);
    esrc[pos] = (unsigned short)src;
}

// ---------------- fused layer v2: 64 dsts x rel-eighth, 3-stage pipeline ----------------
// Prologue stages all binoff boundaries to LDS (meta). Phase r:
//   sB: issue x-row gathers for rel r+1 (srcs loaded last phase, in regs)
//   sA: descriptor ballot + esrc loads for rel r+2
//   sW: W-fragment loads for rel r+1
//   mfma(r): aggbuf[P] x W -> accumulate hblk (f32 LDS)
//   sE: finish aggregation r+1 (sum prefetched rows, rare deg>=3 chain), write aggbuf[P^1]
// Swizzles: aggbuf byte ^ ((row&7)<<4); hblk byte ^ ((row&7)<<4) (2-way = free, G4/m136).

__global__ __launch_bounds__(256, 2) void fused_layer(const unsigned short* __restrict__ xb,
                                                      const unsigned short* __restrict__ Wt,
                                                      const int* __restrict__ binoff,
                                                      const unsigned short* __restrict__ esrc,
                                                      float* __restrict__ hpart) {
    __shared__ __align__(16) char aggbuf[2][DSPAN * 256];   // 2 x 16 KB bf16 rows
    __shared__ __align__(16) char hblk[DSPAN * 512];        // 32 KB f32 accum
    __shared__ int meta[NRMAX][65];
    __shared__ int bbase[3][DSPAN];
    __shared__ int bpack[3][DSPAN];                          // (deg<<8)|dloc

    int b = blockIdx.x;
    int rg = b / NDBLK;
    int dblk = b - rg * NDBLK;
    int dst0 = dblk * DSPAN;
    int r0 = (rg * R_AUG) >> 3;
    int r1 = ((rg + 1) * R_AUG) >> 3;
    int NR = r1 - r0;

    int t = threadIdx.x, w = t >> 6, lane = t & 63;
    int lr = lane & 15, lq = lane >> 4;
    int no = w * 32;
    int prow = ((lr >> 2) << 3) + (lr & 3);

    // ---------- prologue: meta boundaries + hblk zero ----------
    for (int ri = w; ri < NR; ri += 4) {
        int r = r0 + ri;
        int j = dst0 + lane; if (j > N_NODES) j = N_NODES;
        meta[ri][lane] = binoff[r * N_NODES + j];
        if (lane == 0) {
            int j64 = dst0 + 64; if (j64 > N_NODES) j64 = N_NODES;
            meta[ri][64] = binoff[r * N_NODES + j64];
        }
    }
    for (int i = t * 16; i < DSPAN * 512; i += 4096) {
        float4 z = {0.f, 0.f, 0.f, 0.f};
        *(float4*)(hblk + i) = z;
    }
    __syncthreads();

    // ---------- stage lambdas ----------
    // sA(g): descriptor for rel g -> LDS slot g%3; own-wave readback; esrc loads (lane i<16 holds bin w+4i)
    auto sA = [&](int g, int& nb, int& bs, int& dg, int& sv0, int& sv1) {
        nb = 0; bs = 0; dg = 0; sv0 = 0; sv1 = 0;
        if (g >= r1) return;
        int ri = g - r0, g3 = g % 3;
        int bj  = meta[ri][lane];
        int d   = meta[ri][lane + 1] - bj;
        unsigned long long mask = __ballot(d > 0);
        nb = __popcll(mask);
        int cb = __popcll(mask & ((1ull << lane) - 1ull));
        if (d > 0 && (cb & 3) == w) { bbase[g3][cb] = bj; bpack[g3][cb] = (d << 8) | lane; }
        int c = w + 4 * lane;                 // lane i<16 owns row w+4i
        if (lane < 16 && c < nb) {
            bs = bbase[g3][c];                // same-wave LDS write->read: in-order, safe
            dg = bpack[g3][c] >> 8;
            sv0 = esrc[bs];
            sv1 = esrc[bs + (dg > 1 ? 1 : 0)];
        }
    };

    // sB(g): issue x-row gathers (k=0,1) for rel g using regs from sA(g) last phase
    auto sB = [&](int g, int nb1, int dg1, int sv01, int sv11,
                  unsigned* xv0, unsigned* xv1) {
        if (g >= r1) return;
        #pragma unroll
        for (int i = 0; i < 16; i++) {
            int c = w + 4 * i;
            if (c >= nb1) break;                          // wave-uniform
            int s0  = __shfl(sv01, i, 64);
            int dgc = __shfl(dg1, i, 64);
            xv0[i] = *(const unsigned*)(xb + (size_t)s0 * D + lane * 2);
            if (dgc > 1) {
                int s1 = __shfl(sv11, i, 64);
                xv1[i] = *(const unsigned*)(xb + (size_t)s1 * D + lane * 2);
            }
        }
    };

    // sW(g): W fragments for rel g (verified prow-permuted layout)
    auto sW = [&](int g, bf16x8* W0, bf16x8* W1) {
        if (g >= r1) return;
        const unsigned short* Wr = Wt + (size_t)g * D * D;
        #pragma unroll
        for (int ks = 0; ks < 4; ks++) {
            size_t kb = (size_t)ks * 32 + lq * 8;
            W0[ks] = *(const bf16x8*)(Wr + (size_t)(no + prow) * D + kb);
            W1[ks] = *(const bf16x8*)(Wr + (size_t)(no + prow + 4) * D + kb);
        }
    };

    // sE(g): finish aggregation of rel g, write aggbuf[P]
    auto sE = [&](int g, int P, int nb1, int bs1, int dg1,
                  unsigned* xv0, unsigned* xv1) {
        if (g >= r1) return;
        #pragma unroll
        for (int i = 0; i < 16; i++) {
            int c = w + 4 * i;
            if (c >= nb1) break;                          // wave-uniform
            int dgc = __shfl(dg1, i, 64);
            float a0 = bf2f((unsigned short)(xv0[i] & 0xFFFFu));
            float a1 = bf2f((unsigned short)(xv0[i] >> 16));
            if (dgc > 1) {
                a0 += bf2f((unsigned short)(xv1[i] & 0xFFFFu));
                a1 += bf2f((unsigned short)(xv1[i] >> 16));
            }
            if (dgc > 2) {                                // rare tail chain
                int bsc = __shfl(bs1, i, 64);
                for (int k = 2; k < dgc; k++) {
                    int sk = esrc[bsc + k];
                    unsigned xk = *(const unsigned*)(xb + (size_t)sk * D + lane * 2);
                    a0 += bf2f((unsigned short)(xk & 0xFFFFu));
                    a1 += bf2f((unsigned short)(xk >> 16));
                }
            }
            float sc = 1.0f / (float)dgc;
            unsigned pk = (unsigned)f2bf(a0 * sc) | ((unsigned)f2bf(a1 * sc) << 16);
            *(unsigned*)(aggbuf[P] + ((c * 256 + lane * 4) ^ ((c & 7) << 4))) = pk;
        }
    };

    // mfma(g): aggbuf[P] rows x W -> hblk accumulate (wave owns cols no..no+31)
    auto mfmaS = [&](int g, int P, int nb, bf16x8* W0, bf16x8* W1) {
        if (g >= r1 || nb <= 0) return;
        int g3 = g % 3;
        #pragma unroll
        for (int tt = 0; tt < 4; tt++) {
            if (tt * 16 >= nb) break;                     // wave-uniform
            int row = tt * 16 + lr;
            f32x4 c0 = {}, c1 = {};
            #pragma unroll
            for (int ks = 0; ks < 4; ks++) {
                bf16x8 a = *(const bf16x8*)(aggbuf[P] +
                              ((row * 256 + ks * 64 + lq * 16) ^ ((row & 7) << 4)));
                c0 = __builtin_amdgcn_mfma_f32_16x16x32_bf16(W0[ks], a, c0, 0, 0, 0);
                c1 = __builtin_amdgcn_mfma_f32_16x16x32_bf16(W1[ks], a, c1, 0, 0, 0);
            }
            if (row < nb) {
                int dloc = bpack[g3][row] & 0xFF;
                int cb = (no + lq * 8) * 4;
                int sw = (dloc & 7) << 4;
                char* hp0 = hblk + ((dloc * 512 + cb) ^ sw);
                char* hp1 = hblk + ((dloc * 512 + cb + 16) ^ sw);
                float4 h0 = *(float4*)hp0;
                h0.x += c0[0]; h0.y += c0[1]; h0.z += c0[2]; h0.w += c0[3];
                *(float4*)hp0 = h0;
                float4 h1 = *(float4*)hp1;
                h1.x += c1[0]; h1.y += c1[1]; h1.z += c1[2]; h1.w += c1[3];
                *(float4*)hp1 = h1;
            }
        }
    };

    // ---------- software pipeline ----------
    int nbB, bsB, dgB, svB0, svB1;       // rel r+1
    int nbA, bsA, dgA, svA0, svA1;       // rel r+2
    int nbC;                              // rel r (only count needed)
    bf16x8 wc0[4], wc1[4], wn0[4], wn1[4];
    unsigned xv0[16], xv1[16];

    sA(r0, nbB, bsB, dgB, svB0, svB1);
    sB(r0, nbB, dgB, svB0, svB1, xv0, xv1);
    sA(r0 + 1, nbA, bsA, dgA, svA0, svA1);
    sW(r0, wc0, wc1);
    sE(r0, 0, nbB, bsB, dgB, xv0, xv1);
    nbC = nbB;
    nbB = nbA; bsB = bsA; dgB = dgA; svB0 = svA0; svB1 = svA1;
    __syncthreads();

    int P = 0;
    for (int r = r0; r < r1; r++) {
        sB(r + 1, nbB, dgB, svB0, svB1, xv0, xv1);        // gathers first: max latency cover
        sA(r + 2, nbA, bsA, dgA, svA0, svA1);
        sW(r + 1, wn0, wn1);
        mfmaS(r, P, nbC, wc0, wc1);
        sE(r + 1, P ^ 1, nbB, bsB, dgB, xv0, xv1);
        __syncthreads();
        nbC = nbB;
        nbB = nbA; bsB = bsA; dgB = dgA; svB0 = svA0; svB1 = svA1;
        #pragma unroll
        for (int ks = 0; ks < 4; ks++) { wc0[ks] = wn0[ks]; wc1[ks] = wn1[ks]; }
        P ^= 1;
    }

    // ---------- writeback hblk -> hpart[rg] ----------
    {
        int row = t >> 2, seg = t & 3;
        int dst = dst0 + row;
        if (dst < N_NODES) {
            float* outp = hpart + ((size_t)rg * N_NODES + dst) * D + seg * 32;
            int sw = (row & 7) << 4;
            #pragma unroll
            for (int q = 0; q < 8; q++) {
                float4 v = *(float4*)(hblk + ((row * 512 + seg * 128 + q * 16) ^ sw));
                *(float4*)(outp + q * 4) = v;
            }
        }
    }
}

// ---------------- finish: h = act(sum_s hpart[s] + bias) ----------------

__global__ __launch_bounds__(256) void finish(const float* __restrict__ hpart,
                                              const float* __restrict__ bias,
                                              float* __restrict__ hf,
                                              unsigned short* __restrict__ hb,
                                              int dorelu) {
    int i0 = (blockIdx.x * 256 + threadIdx.x) * 8;      // grid 625 covers N_NODES*D exactly
    int c0 = i0 & 127;
    float4 b0 = *(const float4*)(bias + c0), b1 = *(const float4*)(bias + c0 + 4);
    float v0 = b0.x, v1 = b0.y, v2 = b0.z, v3 = b0.w;
    float v4 = b1.x, v5 = b1.y, v6 = b1.z, v7 = b1.w;
    #pragma unroll
    for (int s = 0; s < RSPLIT; s++) {
        const float* p = hpart + (size_t)s * N_NODES * D + i0;
        float4 x0 = *(const float4*)p, x1 = *(const float4*)(p + 4);
        v0 += x0.x; v1 += x0.y; v2 += x0.z; v3 += x0.w;
        v4 += x1.x; v5 += x1.y; v6 += x1.z; v7 += x1.w;
    }
    if (dorelu) {
        uint4 p;
        p.x = (unsigned)f2bf(fmaxf(v0, 0.f)) | ((unsigned)f2bf(fmaxf(v1, 0.f)) << 16);
        p.y = (unsigned)f2bf(fmaxf(v2, 0.f)) | ((unsigned)f2bf(fmaxf(v3, 0.f)) << 16);
        p.z = (unsigned)f2bf(fmaxf(v4, 0.f)) | ((unsigned)f2bf(fmaxf(v5, 0.f)) << 16);
        p.w = (unsigned)f2bf(fmaxf(v6, 0.f)) | ((unsigned)f2bf(fmaxf(v7, 0.f)) << 16);
        *(uint4*)(hb + i0) = p;
    } else {
        float4 o0 = {v0, v1, v2, v3};
        float4 o1 = {v4, v5, v6, v7};
        *(float4*)(hf + i0) = o0;
        *(float4*)(hf + i0 + 4) = o1;
    }
}

// ---------------- scoring: 4 items/wave (16 lanes x 2 float4 each) ----------------

__global__ __launch_bounds__(256) void score_kernel(const int* __restrict__ batch,
                                                    const float* __restrict__ h2,
                                                    const float* __restrict__ rels,
                                                    float* __restrict__ out) {
    int t = threadIdx.x;
    int wv = t >> 6, q = (t & 63) >> 4, sl = t & 15;
    int i = blockIdx.x * 16 + wv * 4 + q;     // grid 4096 covers 65536 exactly
    int bs = batch[3*i], bp = batch[3*i+1], bo = batch[3*i+2];
    const float* sp = h2   + (size_t)bs * D + sl * 8;
    const float* pp = rels + (size_t)bp * D + sl * 8;
    const float* op = h2   + (size_t)bo * D + sl * 8;
    float4 s0 = *(const float4*)sp,      s1 = *(const float4*)(sp + 4);
    float4 p0 = *(const float4*)pp,      p1 = *(const float4*)(pp + 4);
    float4 o0 = *(const float4*)op,      o1 = *(const float4*)(op + 4);
    float v = s0.x * p0.x * o0.x + s0.y * p0.y * o0.y + s0.z * p0.z * o0.z + s0.w * p0.w * o0.w
            + s1.x * p1.x * o1.x + s1.y * p1.y * o1.y + s1.z * p1.z * o1.z + s1.w * p1.w * o1.w;
    #pragma unroll
    for (int off = 8; off > 0; off >>= 1) v += __shfl_down(v, off, 16);
    if (sl == 0) out[i] = v;
}

// ---------------- host ----------------

extern "C" void kernel_launch(void* const* d_in, const int* in_sizes, int n_in,
                              void* d_out, int out_size, void* d_ws, size_t ws_size,
                              hipStream_t stream) {
    const int*   graph = (const int*)  d_in[0];
    const int*   batch = (const int*)  d_in[1];
    const float* emb   = (const float*)d_in[2];
    const float* W1    = (const float*)d_in[3];
    const float* b1    = (const float*)d_in[4];
    const float* W2    = (const float*)d_in[5];
    const float* b2    = (const float*)d_in[6];
    const float* rels  = (const float*)d_in[7];
    float* out = (float*)d_out;

    char* base = (char*)d_ws;
    size_t off = 0;
    auto take = [&](size_t bytes) -> char* {
        char* q = base + off;
        off += (bytes + 255) & ~(size_t)255;
        return q;
    };
    int*            deg     = (int*)           take((size_t)NP * 4);
    int*            binoff  = (int*)           take((size_t)(NP + 1) * 4);
    int*            cursor  = (int*)           take((size_t)NP * 4);
    int*            ppart   = (int*)           take((size_t)NPB4 * 4);
    unsigned short* esrc    = (unsigned short*)take((size_t)E_AUG * 2);
    unsigned short* xb      = (unsigned short*)take((size_t)N_NODES * D * 2);
    unsigned short* h1b     = (unsigned short*)take((size_t)N_NODES * D * 2);
    float*          h2      = (float*)         take((size_t)N_NODES * D * 4);
    unsigned short* W1t     = (unsigned short*)take((size_t)R_AUG * D * D * 2);
    unsigned short* W2t     = (unsigned short*)take((size_t)R_AUG * D * D * 2);
    float*          hpart   = (float*)         take((size_t)RSPLIT * N_NODES * D * 4);

    hipMemsetAsync(deg, 0, (size_t)NP * 4, stream);
    prep_all<<<dim3(HIST_BLOCKS + TW_BLOCKS + PREPX_BLOCKS), 256, 0, stream>>>(
        emb, xb, W1, W2, W1t, W2t, graph, deg);
    scan_a<<<dim3(NPB4), 256, 0, stream>>>(deg, binoff, ppart);
    scan_b<<<dim3(1), 256, 0, stream>>>(ppart, binoff);
    scan_c<<<dim3(NPB4), 256, 0, stream>>>(binoff, ppart, cursor);
    scatter_edges<<<dim3(SCAT_BLOCKS), 256, 0, stream>>>(graph, cursor, esrc);

    fused_layer<<<dim3(FUSE_BLOCKS), 256, 0, stream>>>(xb, W1t, binoff, esrc, hpart);
    finish<<<dim3(625), 256, 0, stream>>>(hpart, b1, (float*)0, h1b, 1);
    fused_layer<<<dim3(FUSE_BLOCKS), 256, 0, stream>>>(h1b, W2t, binoff, esrc, hpart);
    finish<<<dim3(625), 256, 0, stream>>>(hpart, b2, h2, (unsigned short*)0, 0);
    score_kernel<<<dim3(N_BATCH / 16), 256, 0, stream>>>(batch, h2, rels, out);
}